// Round 13
// baseline (428.179 us; speedup 1.0000x reference)
//
#include <hip/hip_runtime.h>
#include <hip/hip_cooperative_groups.h>
#include <hip/hip_bf16.h>

namespace cg = cooperative_groups;

// Dims (fixed by the reference)
#define B_   8
#define L_   512
#define DIN  128
#define DM   512
#define NLAY 2
#define DI   1024
#define DS   16
#define DTR  32
#define BL   (B_ * L_)   // 4096
#define KS   8
#define CL   64          // scan chunk length
#define NCH  (L_ / CL)   // 8
#define NBLK 512

typedef short bf16x8 __attribute__((ext_vector_type(8)));
typedef float floatx4 __attribute__((ext_vector_type(4)));

__device__ __forceinline__ unsigned short f2bf(float f) {
    unsigned int u = __float_as_uint(f);
    unsigned int r = (u + 0x7FFF + ((u >> 16) & 1)) >> 16;   // RNE
    return (unsigned short)r;
}
__device__ __forceinline__ float bf2f(unsigned short u) {
    return __uint_as_float((unsigned int)u << 16);
}

#if __has_builtin(__builtin_amdgcn_exp2f)
#define EXP2(x) __builtin_amdgcn_exp2f(x)
#else
#define EXP2(x) __expf((x) * 0.69314718056f)
#endif

template <int CTRL>
__device__ __forceinline__ float dpp_shr_add(float v) {
    int sh = __builtin_amdgcn_update_dpp(0, __float_as_int(v), CTRL, 0xF, 0xF, true);
    return v + __int_as_float(sh);
}

struct KParams {
    const float *x, *proj_in_w, *proj_in_b, *conv_w, *conv_b, *x_proj_w,
                *dt_proj_w, *dt_proj_b, *A_log, *Dm, *in_proj_w, *out_proj_w,
                *cls_w1, *cls_b1, *cls_w2, *cls_b2;
    float *out;
    float *xcb, *xdbl, *xpart, *hm;
    unsigned short *xzb, *xbf, *hbf, *ysbf, *wpin, *win, *wout;
};

// ===========================================================================
// Stage bodies (shared by mono kernel and fallback wrappers)
// ===========================================================================

// --- conversions + zero hm. Tasks 0..1825. --------------------------------
__device__ void stage_cvt(const float* x, unsigned short* xbf,
                          const float* pw, unsigned short* wpin,
                          const float* iw, unsigned short* win,
                          const float* ow, unsigned short* wout,
                          float* hm, int task, int tid) {
    if (task >= 1824) {
        int i = (task - 1824) * 2048 + tid * 8;
        float4 z = make_float4(0.f, 0.f, 0.f, 0.f);
        *(float4*)(hm + i) = z;
        *(float4*)(hm + i + 4) = z;
        return;
    }
    const float* src; unsigned short* dst; int off;
    if      (task < 256)  { src = x;  dst = xbf;  off = task; }
    else if (task < 288)  { src = pw; dst = wpin; off = task - 256; }
    else if (task < 1312) { src = iw; dst = win;  off = task - 288; }
    else                  { src = ow; dst = wout; off = task - 1312; }
    int i = (off * 256 + tid) * 8;
    float4 a = *(const float4*)(src + i);
    float4 b = *(const float4*)(src + i + 4);
    unsigned short o[8];
    o[0] = f2bf(a.x); o[1] = f2bf(a.y); o[2] = f2bf(a.z); o[3] = f2bf(a.w);
    o[4] = f2bf(b.x); o[5] = f2bf(b.y); o[6] = f2bf(b.z); o[7] = f2bf(b.w);
    *(uint4*)(dst + i) = *(uint4*)o;
}

// --- bf16 MFMA GEMM 128x64 (N=512). LDS: 15616 B. -------------------------
__device__ void stage_gemm_n64(const unsigned short* __restrict__ A,
                               const unsigned short* __restrict__ W,
                               const float* bias, unsigned short* Cb,
                               int meanmode, float* hm, int K,
                               int bxx, int byy, unsigned char* sm, int tid) {
    unsigned short* As = (unsigned short*)sm;            // 128*40*2 = 10240
    unsigned short* Ws = (unsigned short*)(sm + 10240);  // 64*40*2  = 5120
    float* colsum = (float*)(sm + 15360);                // 256

    const int arow  = tid >> 1;
    const int ahalf = tid & 1;
    const long aBase = (long)(byy * 128 + arow) * K + ahalf * 16;
    const int  albase = arow * 40 + ahalf * 16;
    const int wrow = tid >> 2;
    const int wq   = tid & 3;
    const long wBase = (long)(bxx * 64 + wrow) * K + wq * 8;
    const int  wlbase = wrow * 40 + wq * 8;

    const int lane = tid & 63;
    const int wv   = tid >> 6;
    const int wm   = wv * 32;
    const int lr   = lane & 15;
    const int q    = lane >> 4;

    floatx4 acc[2][4];
#pragma unroll
    for (int i = 0; i < 2; ++i)
#pragma unroll
        for (int j = 0; j < 4; ++j)
#pragma unroll
            for (int r = 0; r < 4; ++r) acc[i][j][r] = 0.f;

    for (int k0 = 0; k0 < K; k0 += 32) {
        __syncthreads();
        const unsigned short* ap = A + aBase + k0;
        uint4 a0 = *(const uint4*)ap;
        uint4 a1 = *(const uint4*)(ap + 8);
        uint4 w0 = *(const uint4*)(W + wBase + k0);
        *(uint4*)(As + albase)     = a0;
        *(uint4*)(As + albase + 8) = a1;
        *(uint4*)(Ws + wlbase)     = w0;
        __syncthreads();

        bf16x8 af[2], bfr[4];
#pragma unroll
        for (int i = 0; i < 2; ++i)
            af[i] = *(const bf16x8*)(As + (wm + i * 16 + lr) * 40 + q * 8);
#pragma unroll
        for (int j = 0; j < 4; ++j)
            bfr[j] = *(const bf16x8*)(Ws + (j * 16 + lr) * 40 + q * 8);
#pragma unroll
        for (int i = 0; i < 2; ++i)
#pragma unroll
            for (int j = 0; j < 4; ++j)
                acc[i][j] = __builtin_amdgcn_mfma_f32_16x16x32_bf16(
                    af[i], bfr[j], acc[i][j], 0, 0, 0);
    }

    if (meanmode) {
        __syncthreads();
        if (tid < 64) colsum[tid] = 0.f;
        __syncthreads();
#pragma unroll
        for (int j = 0; j < 4; ++j) {
            float pp = 0.f;
#pragma unroll
            for (int i = 0; i < 2; ++i)
#pragma unroll
                for (int r = 0; r < 4; ++r) pp += acc[i][j][r];
            atomicAdd(&colsum[j * 16 + lr], pp);
        }
        __syncthreads();
        if (tid < 64) {
            const int b = byy >> 2;
            atomicAdd(&hm[b * DM + bxx * 64 + tid],
                      colsum[tid] * (1.f / (float)L_));
        }
        return;
    }

    float bj[4] = {0.f, 0.f, 0.f, 0.f};
    if (bias) {
#pragma unroll
        for (int j = 0; j < 4; ++j)
            bj[j] = bias[bxx * 64 + j * 16 + lr];
    }
#pragma unroll
    for (int i = 0; i < 2; ++i) {
#pragma unroll
        for (int r = 0; r < 4; ++r) {
            const int  crow = byy * 128 + wm + i * 16 + q * 4 + r;
            const long base = (long)crow * DM + bxx * 64 + lr;
#pragma unroll
            for (int j = 0; j < 4; ++j)
                Cb[base + j * 16] = f2bf(acc[i][j][r] + bj[j]);
        }
    }
}

// --- bf16 MFMA GEMM 128x128 (in_proj). LDS: 20480 B. -----------------------
__device__ void stage_gemm_128(const unsigned short* __restrict__ A,
                               const unsigned short* __restrict__ W,
                               unsigned short* Cb, int N, int K,
                               int bxx, int byy, unsigned char* sm, int tid) {
    unsigned short* As = (unsigned short*)sm;
    unsigned short* Ws = (unsigned short*)(sm + 10240);

    const int row  = tid >> 1;
    const int half = tid & 1;
    const long aBase = (long)(byy * 128 + row) * K + half * 16;
    const long wBase = (long)(bxx * 128 + row) * K + half * 16;
    const int  lbase = row * 40 + half * 16;

    const int lane = tid & 63;
    const int wv   = tid >> 6;
    const int wm   = (wv >> 1) * 64;
    const int wn   = (wv & 1) * 64;
    const int lr   = lane & 15;
    const int q    = lane >> 4;

    floatx4 acc[4][4];
#pragma unroll
    for (int i = 0; i < 4; ++i)
#pragma unroll
        for (int j = 0; j < 4; ++j)
#pragma unroll
            for (int r = 0; r < 4; ++r) acc[i][j][r] = 0.f;

    for (int k0 = 0; k0 < K; k0 += 32) {
        __syncthreads();
        const unsigned short* ap = A + aBase + k0;
        const unsigned short* wp = W + wBase + k0;
        uint4 a0 = *(const uint4*)ap;
        uint4 a1 = *(const uint4*)(ap + 8);
        uint4 w0 = *(const uint4*)wp;
        uint4 w1 = *(const uint4*)(wp + 8);
        *(uint4*)(As + lbase)     = a0;
        *(uint4*)(As + lbase + 8) = a1;
        *(uint4*)(Ws + lbase)     = w0;
        *(uint4*)(Ws + lbase + 8) = w1;
        __syncthreads();

        bf16x8 af[4], bfr[4];
#pragma unroll
        for (int i = 0; i < 4; ++i)
            af[i] = *(const bf16x8*)(As + (wm + i * 16 + lr) * 40 + q * 8);
#pragma unroll
        for (int j = 0; j < 4; ++j)
            bfr[j] = *(const bf16x8*)(Ws + (wn + j * 16 + lr) * 40 + q * 8);
#pragma unroll
        for (int i = 0; i < 4; ++i)
#pragma unroll
            for (int j = 0; j < 4; ++j)
                acc[i][j] = __builtin_amdgcn_mfma_f32_16x16x32_bf16(
                    af[i], bfr[j], acc[i][j], 0, 0, 0);
    }

#pragma unroll
    for (int i = 0; i < 4; ++i) {
#pragma unroll
        for (int r = 0; r < 4; ++r) {
            const int  crow = byy * 128 + wm + i * 16 + q * 4 + r;
            const long base = (long)crow * N + bxx * 128 + wn + lr;
#pragma unroll
            for (int j = 0; j < 4; ++j)
                Cb[base + j * 16] = f2bf(acc[i][j][r]);
        }
    }
}

// --- fused conv+silu + x_proj split-K partials. LDS: 8704 B. ---------------
__device__ void stage_xprojconv(const unsigned short* __restrict__ xzb,
                                const float* cw, const float* cb,
                                const float* __restrict__ W,
                                float* P, float* xcout,
                                int ks, int byy, unsigned char* sm, int tid) {
    float (*As)[68] = (float(*)[68])sm;            // 16x68x4 = 4352
    float (*Ws)[68] = (float(*)[68])(sm + 4352);

    const int tx   = tid & 15;
    const int ty   = tid >> 4;
    const int lrow = tid >> 2;
    const int lk   = (tid & 3) << 2;
    const int kbase = ks * (DI / KS);

    const int m = byy * 64 + lrow;
    const int t = m & (L_ - 1);
    const float* Wp = W + lrow * DI + kbase + lk;

    float acc[4][4] = {};

    for (int k0 = 0; k0 < DI / KS; k0 += 16) {
        const int dcol = kbase + k0 + lk;
        float4 cbv = *(const float4*)(cb + dcol);
        float sums[4] = {cbv.x, cbv.y, cbv.z, cbv.w};
        float4 cwq[4];
#pragma unroll
        for (int qq = 0; qq < 4; ++qq) cwq[qq] = *(const float4*)(cw + (dcol + qq) * 4);
#pragma unroll
        for (int w = 0; w < 4; ++w) {
            int tw = t - 3 + w;
            if (tw >= 0) {
                const uint2 up = *(const uint2*)(xzb + (long)(m - 3 + w) * (2 * DI) + dcol);
                float x0 = __uint_as_float(up.x << 16);
                float x1 = __uint_as_float(up.x & 0xffff0000u);
                float x2 = __uint_as_float(up.y << 16);
                float x3 = __uint_as_float(up.y & 0xffff0000u);
                sums[0] += ((const float*)&cwq[0])[w] * x0;
                sums[1] += ((const float*)&cwq[1])[w] * x1;
                sums[2] += ((const float*)&cwq[2])[w] * x2;
                sums[3] += ((const float*)&cwq[3])[w] * x3;
            }
        }
        float4 a4;
#pragma unroll
        for (int qq = 0; qq < 4; ++qq)
            ((float*)&a4)[qq] = sums[qq] / (1.f + __expf(-sums[qq]));
        float4 wv = *(const float4*)(Wp + k0);
        *(float4*)(xcout + (long)m * DI + dcol) = a4;

        __syncthreads();
        As[lk + 0][lrow] = a4.x; As[lk + 1][lrow] = a4.y;
        As[lk + 2][lrow] = a4.z; As[lk + 3][lrow] = a4.w;
        Ws[lk + 0][lrow] = wv.x; Ws[lk + 1][lrow] = wv.y;
        Ws[lk + 2][lrow] = wv.z; Ws[lk + 3][lrow] = wv.w;
        __syncthreads();
#pragma unroll
        for (int k = 0; k < 16; ++k) {
            const float4 a44 = *(const float4*)&As[k][ty << 2];
            const float4 w4  = *(const float4*)&Ws[k][tx << 2];
            acc[0][0] += a44.x * w4.x; acc[0][1] += a44.x * w4.y;
            acc[0][2] += a44.x * w4.z; acc[0][3] += a44.x * w4.w;
            acc[1][0] += a44.y * w4.x; acc[1][1] += a44.y * w4.y;
            acc[1][2] += a44.y * w4.z; acc[1][3] += a44.y * w4.w;
            acc[2][0] += a44.z * w4.x; acc[2][1] += a44.z * w4.y;
            acc[2][2] += a44.z * w4.z; acc[2][3] += a44.z * w4.w;
            acc[3][0] += a44.w * w4.x; acc[3][1] += a44.w * w4.y;
            acc[3][2] += a44.w * w4.z; acc[3][3] += a44.w * w4.w;
        }
    }

    float* outp = P + (long)ks * (BL * 64)
                + (byy * 64 + (ty << 2)) * 64 + (tx << 2);
#pragma unroll
    for (int i = 0; i < 4; ++i)
        *(float4*)(outp + i * 64) = make_float4(acc[i][0], acc[i][1],
                                                acc[i][2], acc[i][3]);
}

// --- x_proj split-K reduce. Tasks 0..255. ----------------------------------
__device__ void stage_reduce(const float* __restrict__ P, float* xdbl,
                             int task, int tid) {
    int i = (task * 256 + tid) * 4;
    float4 s = *(const float4*)(P + i);
#pragma unroll
    for (int k = 1; k < KS; ++k) {
        float4 pp = *(const float4*)(P + (long)k * (BL * 64) + i);
        s.x += pp.x; s.y += pp.y; s.z += pp.z; s.w += pp.w;
    }
    *(float4*)(xdbl + i) = s;
}

// --- monolithic scan, CL=64, dtw in regs. LDS: 30976 B. --------------------
__device__ void stage_scan(const float* __restrict__ xc,
                           const float* __restrict__ xdbl,
                           const float* A_log, const float* dtw,
                           const float* dtpb, const float* Dm,
                           const unsigned short* __restrict__ xzb,
                           unsigned short* ysb16,
                           int task, unsigned char* sm, int tid) {
    float (*sxd)[36]   = (float(*)[36])(sm);            // 64x36x4 = 9216
    float4 (*sdp)[17]  = (float4(*)[17])(sm + 9216);    // 32x17x16 = 8704
    float4 (*sbc4)[17] = (float4(*)[17])(sm + 17920);   // 8704
    float (*sy)[68]    = (float(*)[68])(sm + 26624);    // 16x68x4 = 4352

    const int s    = tid & 15;
    const int grp  = tid >> 4;
    const int bd0  = task * 16;
    const int b    = bd0 >> 10;
    const int d0   = bd0 & (DI - 1);
    const int mb0  = b * L_;

    const int j  = tid & 15;
    const int tt = tid >> 4;

    const float a    = -__expf(A_log[(d0 + grp) * DS + s]);
    const float bias = dtpb[d0 + j];
    const float dmv  = Dm[d0 + j];
    float4 wreg[8];
#pragma unroll
    for (int k = 0; k < 8; ++k)
        wreg[k] = *(const float4*)(dtw + (d0 + j) * DTR + k * 4);

    float  rxc[4], rB[4], rC[4], rz[4];
    float2 rxd[4];
#pragma unroll
    for (int i = 0; i < 4; ++i) {
        int m = mb0 + tt + 16 * i;
        rxc[i] = xc[m * DI + d0 + j];
        rxd[i] = *(const float2*)(xdbl + m * 64 + j * 2);
        rB[i]  = xdbl[m * 64 + DTR + j];
        rC[i]  = xdbl[m * 64 + DTR + DS + j];
        rz[i]  = bf2f(xzb[(long)m * (2 * DI) + DI + d0 + j]);
    }

    float state = 0.f;

    for (int c = 0; c < NCH; ++c) {
        const int mbase = mb0 + c * CL;
        float xcur[4], zcur[4];
#pragma unroll
        for (int i = 0; i < 4; ++i) { xcur[i] = rxc[i]; zcur[i] = rz[i]; }

        __syncthreads();   // prev chunk LDS fully consumed
#pragma unroll
        for (int i = 0; i < 4; ++i) {
            int t = tt + 16 * i;
            *(float2*)&sxd[t][j * 2] = rxd[i];
            ((float2*)&sbc4[t >> 1][j])[t & 1] = make_float2(rB[i], rC[i]);
        }
        __syncthreads();

        if (c < NCH - 1) {
#pragma unroll
            for (int i = 0; i < 4; ++i) {
                int m = mbase + CL + tt + 16 * i;
                rxc[i] = xc[m * DI + d0 + j];
                rxd[i] = *(const float2*)(xdbl + m * 64 + j * 2);
                rB[i]  = xdbl[m * 64 + DTR + j];
                rC[i]  = xdbl[m * 64 + DTR + DS + j];
                rz[i]  = bf2f(xzb[(long)m * (2 * DI) + DI + d0 + j]);
            }
        }

        // dt-projection: (dt*log2e, dt*xc) per (t,d)
#pragma unroll
        for (int i = 0; i < 4; ++i) {
            int t = tt + 16 * i;
            float acc = bias;
#pragma unroll
            for (int k = 0; k < 8; ++k) {
                float4 xv = *(const float4*)&sxd[t][k * 4];
                acc += xv.x * wreg[k].x + xv.y * wreg[k].y
                     + xv.z * wreg[k].z + xv.w * wreg[k].w;
            }
            float dt = (acc > 20.f) ? acc : __logf(1.f + __expf(acc));
            ((float2*)&sdp[t >> 1][j])[t & 1] =
                make_float2(dt * 1.44269504f, dt * xcur[i]);
        }
        __syncthreads();

        for (int t4 = 0; t4 < CL; t4 += 4) {
            float ybuf[4];
#pragma unroll
            for (int h = 0; h < 2; ++h) {
                const int t2 = (t4 >> 1) + h;
                const float4 dp = sdp[t2][grp];
                const float4 bc = sbc4[t2][s];
                {
                    const float dA = EXP2(dp.x * a);
                    state = fmaf(dA, state, dp.y * bc.x);
                    float contrib = state * bc.y;
                    contrib = dpp_shr_add<0x111>(contrib);
                    contrib = dpp_shr_add<0x112>(contrib);
                    contrib = dpp_shr_add<0x114>(contrib);
                    contrib = dpp_shr_add<0x118>(contrib);
                    ybuf[h * 2] = contrib;
                }
                {
                    const float dA = EXP2(dp.z * a);
                    state = fmaf(dA, state, dp.w * bc.z);
                    float contrib = state * bc.w;
                    contrib = dpp_shr_add<0x111>(contrib);
                    contrib = dpp_shr_add<0x112>(contrib);
                    contrib = dpp_shr_add<0x114>(contrib);
                    contrib = dpp_shr_add<0x118>(contrib);
                    ybuf[h * 2 + 1] = contrib;
                }
            }
            if (s == 15) *(float4*)&sy[grp][t4] = *(float4*)ybuf;
        }
        __syncthreads();

#pragma unroll
        for (int i = 0; i < 4; ++i) {
            int t = tt + 16 * i;
            float z = zcur[i];
            float sz = z / (1.f + __expf(-z));
            float val = (sy[j][t] + xcur[i] * dmv) * sz;
            ysb16[(mbase + t) * DI + d0 + j] = f2bf(val);
        }
    }
}

// --- classifier head from hm. Tasks 0..7, 256 thr. LDS: 2304 B. ------------
__device__ void stage_meancls(const float* hm, const float* w1,
                              const float* b1, const float* w2,
                              const float* b2, float* out,
                              int b, unsigned char* sm, int tid) {
    float* shm = (float*)sm;            // 512 floats
    float* su  = (float*)(sm + 2048);   // 64 floats
    shm[tid]       = hm[b * DM + tid];
    shm[tid + 256] = hm[b * DM + tid + 256];
    __syncthreads();

    const int j = tid >> 2, sl = tid & 3;   // 64 units x 4 slices of 128
    const float* wr = w1 + j * DM + sl * 128;
    const float* hb = shm + sl * 128;
    float pp = 0.f;
    for (int k = 0; k < 128; k += 4)
        pp += hb[k] * wr[k] + hb[k+1] * wr[k+1]
            + hb[k+2] * wr[k+2] + hb[k+3] * wr[k+3];
    pp += __shfl_xor(pp, 1);
    pp += __shfl_xor(pp, 2);
    if (sl == 0) su[j] = fmaxf(pp + b1[j], 0.f) * w2[j];
    __syncthreads();
    if (tid < 64) {
        float v = su[tid];
#pragma unroll
        for (int off = 32; off; off >>= 1) v += __shfl_down(v, off);
        if (tid == 0) out[b] = v + b2[0];
    }
}

// ===========================================================================
// Cooperative mega-kernel (grid-stride; 30976 B arena => >=2 blocks/CU even
// under 64 KiB/CU accounting).
// ===========================================================================
__global__ __launch_bounds__(256) void mamba_mono(KParams p) {
    cg::grid_group grid = cg::this_grid();
    __shared__ __attribute__((aligned(16))) unsigned char sm[30976];
    const int tid  = threadIdx.x;
    const int bx   = blockIdx.x;
    const int nblk = gridDim.x;

    for (int task = bx; task < 1826; task += nblk)
        stage_cvt(p.x, p.xbf, p.proj_in_w, p.wpin, p.in_proj_w, p.win,
                  p.out_proj_w, p.wout, p.hm, task, tid);
    grid.sync();

    for (int task = bx; task < 256; task += nblk)
        stage_gemm_n64(p.xbf, p.wpin, p.proj_in_b, p.hbf, 0, nullptr, DIN,
                       task & 7, task >> 3, sm, tid);
    grid.sync();

    for (int l = 0; l < NLAY; ++l) {
        for (int task = bx; task < 512; task += nblk)
            stage_gemm_128(p.hbf, p.win + l * 2 * DI * DM, p.xzb, 2 * DI, DM,
                           task & 15, task >> 4, sm, tid);
        grid.sync();

        for (int task = bx; task < 512; task += nblk)
            stage_xprojconv(p.xzb, p.conv_w + l * DI * 4, p.conv_b + l * DI,
                            p.x_proj_w + l * 64 * DI, p.xpart, p.xcb,
                            task & 7, task >> 3, sm, tid);
        grid.sync();

        for (int task = bx; task < 256; task += nblk)
            stage_reduce(p.xpart, p.xdbl, task, tid);
        grid.sync();

        for (int task = bx; task < 512; task += nblk)
            stage_scan(p.xcb, p.xdbl, p.A_log + l * DI * DS,
                       p.dt_proj_w + l * DI * DTR, p.dt_proj_b + l * DI,
                       p.Dm + l * DI, p.xzb, p.ysbf, task, sm, tid);
        grid.sync();

        for (int task = bx; task < 256; task += nblk) {
            if (l == NLAY - 1)
                stage_gemm_n64(p.ysbf, p.wout + l * DM * DI, nullptr, nullptr,
                               1, p.hm, DI, task & 7, task >> 3, sm, tid);
            else
                stage_gemm_n64(p.ysbf, p.wout + l * DM * DI, nullptr, p.hbf,
                               0, nullptr, DI, task & 7, task >> 3, sm, tid);
        }
        grid.sync();
    }

    for (int task = bx; task < 8; task += nblk)
        stage_meancls(p.hm, p.cls_w1, p.cls_b1, p.cls_w2, p.cls_b2, p.out,
                      task, sm, tid);
}

// ===========================================================================
// Fallback wrappers (R11-equivalent multi-kernel path)
// ===========================================================================
__global__ __launch_bounds__(256) void k_cvt(
    const float* x, unsigned short* xbf, const float* pw, unsigned short* wpin,
    const float* iw, unsigned short* win, const float* ow, unsigned short* wout,
    float* hm) {
    stage_cvt(x, xbf, pw, wpin, iw, win, ow, wout, hm, blockIdx.x, threadIdx.x);
}
__global__ __launch_bounds__(256) void k_gemm_n64(
    const unsigned short* A, const unsigned short* W, const float* bias,
    unsigned short* Cb, int meanmode, float* hm, int K) {
    __shared__ __attribute__((aligned(16))) unsigned char sm[15616];
    stage_gemm_n64(A, W, bias, Cb, meanmode, hm, K,
                   blockIdx.x, blockIdx.y, sm, threadIdx.x);
}
__global__ __launch_bounds__(256) void k_gemm_128(
    const unsigned short* A, const unsigned short* W, unsigned short* Cb,
    int N, int K) {
    __shared__ __attribute__((aligned(16))) unsigned char sm[20480];
    stage_gemm_128(A, W, Cb, N, K, blockIdx.x, blockIdx.y, sm, threadIdx.x);
}
__global__ __launch_bounds__(256) void k_xprojconv(
    const unsigned short* xzb, const float* cw, const float* cb,
    const float* W, float* P, float* xcout) {
    __shared__ __attribute__((aligned(16))) unsigned char sm[8704];
    stage_xprojconv(xzb, cw, cb, W, P, xcout,
                    blockIdx.x, blockIdx.y, sm, threadIdx.x);
}
__global__ __launch_bounds__(256) void k_reduce(const float* P, float* xdbl) {
    stage_reduce(P, xdbl, blockIdx.x, threadIdx.x);
}
__global__ __launch_bounds__(256) void k_scan(
    const float* xc, const float* xdbl, const float* A_log, const float* dtw,
    const float* dtpb, const float* Dm, const unsigned short* xzb,
    unsigned short* ysb16) {
    __shared__ __attribute__((aligned(16))) unsigned char sm[30976];
    stage_scan(xc, xdbl, A_log, dtw, dtpb, Dm, xzb, ysb16,
               blockIdx.x, sm, threadIdx.x);
}
__global__ __launch_bounds__(256) void k_meancls(
    const float* hm, const float* w1, const float* b1,
    const float* w2, const float* b2, float* out) {
    __shared__ __attribute__((aligned(16))) unsigned char sm[2304];
    stage_meancls(hm, w1, b1, w2, b2, out, blockIdx.x, sm, threadIdx.x);
}

// ---------------------------------------------------------------------------
extern "C" void kernel_launch(void* const* d_in, const int* in_sizes, int n_in,
                              void* d_out, int out_size, void* d_ws, size_t ws_size,
                              hipStream_t stream) {
    KParams p;
    p.x          = (const float*)d_in[0];
    p.proj_in_w  = (const float*)d_in[1];
    p.proj_in_b  = (const float*)d_in[2];
    p.in_proj_w  = (const float*)d_in[3];
    p.conv_w     = (const float*)d_in[4];
    p.conv_b     = (const float*)d_in[5];
    p.x_proj_w   = (const float*)d_in[6];
    p.dt_proj_w  = (const float*)d_in[7];
    p.dt_proj_b  = (const float*)d_in[8];
    p.A_log      = (const float*)d_in[9];
    p.Dm         = (const float*)d_in[10];
    p.out_proj_w = (const float*)d_in[11];
    p.cls_w1     = (const float*)d_in[12];
    p.cls_b1     = (const float*)d_in[13];
    p.cls_w2     = (const float*)d_in[14];
    p.cls_b2     = (const float*)d_in[15];
    p.out        = (float*)d_out;

    float* ws   = (float*)d_ws;
    float* h    = ws;                       // layout keeper
    float* xzf  = h    + BL * DM;           // bf16 xz region
    p.xcb       = xzf  + BL * 2 * DI;
    p.xdbl      = p.xcb + BL * DI;
    float* scr  = p.xdbl + BL * 64;
    p.hm        = scr  + 2 * BL * DI;
    float* hmp  = p.hm + B_ * DM;           // layout keeper
    p.xpart     = scr;

    p.xzb  = (unsigned short*)xzf;
    unsigned short* u16 = (unsigned short*)(hmp + 64 * DM);
    p.xbf  = u16;
    p.hbf  = p.xbf  + BL * DIN;
    p.ysbf = p.hbf  + BL * DM;
    p.wpin = p.ysbf + BL * DI;
    p.win  = p.wpin + DM * DIN;
    p.wout = p.win  + NLAY * 2 * DI * DM;

    // --- try cooperative mega-kernel; fall back to multi-kernel path -------
    bool coop_ok = false;
    int occ = 0;
    hipError_t e = hipOccupancyMaxActiveBlocksPerMultiprocessor(
        &occ, (const void*)mamba_mono, 256, 0);
    if (e == hipSuccess && occ > 0) {
        int nblk = occ * 256;            // 256 CUs on MI355X
        if (nblk > NBLK) nblk = NBLK;
        void* kargs[] = { (void*)&p };
        e = hipLaunchCooperativeKernel((const void*)mamba_mono, dim3(nblk),
                                       dim3(256), kargs, 0, stream);
        coop_ok = (e == hipSuccess);
    }
    if (!coop_ok) {
        (void)hipGetLastError();   // clear sticky error from rejected launch
        k_cvt<<<1826, 256, 0, stream>>>(p.x, p.xbf, p.proj_in_w, p.wpin,
                                        p.in_proj_w, p.win, p.out_proj_w,
                                        p.wout, p.hm);
        k_gemm_n64<<<dim3(8, 32), 256, 0, stream>>>(
            p.xbf, p.wpin, p.proj_in_b, p.hbf, 0, nullptr, DIN);
        for (int l = 0; l < NLAY; ++l) {
            k_gemm_128<<<dim3(16, 32), 256, 0, stream>>>(
                p.hbf, p.win + l * 2 * DI * DM, p.xzb, 2 * DI, DM);
            k_xprojconv<<<dim3(8, 64), 256, 0, stream>>>(
                p.xzb, p.conv_w + l * DI * 4, p.conv_b + l * DI,
                p.x_proj_w + l * 64 * DI, p.xpart, p.xcb);
            k_reduce<<<256, 256, 0, stream>>>(p.xpart, p.xdbl);
            k_scan<<<512, 256, 0, stream>>>(
                p.xcb, p.xdbl, p.A_log + l * DI * DS,
                p.dt_proj_w + l * DI * DTR, p.dt_proj_b + l * DI,
                p.Dm + l * DI, p.xzb, p.ysbf);
            if (l == NLAY - 1)
                k_gemm_n64<<<dim3(8, 32), 256, 0, stream>>>(
                    p.ysbf, p.wout + l * DM * DI, nullptr, nullptr, 1, p.hm, DI);
            else
                k_gemm_n64<<<dim3(8, 32), 256, 0, stream>>>(
                    p.ysbf, p.wout + l * DM * DI, nullptr, p.hbf, 0, nullptr, DI);
        }
        k_meancls<<<8, 256, 0, stream>>>(p.hm, p.cls_w1, p.cls_b1,
                                         p.cls_w2, p.cls_b2, p.out);
    }
}

// Round 14
// 374.793 us; speedup vs baseline: 1.1424x; 1.1424x over previous
//
#include <hip/hip_runtime.h>
#include <hip/hip_bf16.h>

// Dims (fixed by the reference)
#define B_   8
#define L_   512
#define DIN  128
#define DM   512
#define NLAY 2
#define DI   1024
#define DS   16
#define DTR  32
#define BL   (B_ * L_)   // 4096
#define KS   8
#define CL   128         // scan chunk length
#define NCH  (L_ / CL)   // 4

typedef short bf16x8 __attribute__((ext_vector_type(8)));
typedef float floatx4 __attribute__((ext_vector_type(4)));

__device__ __forceinline__ unsigned short f2bf(float f) {
    unsigned int u = __float_as_uint(f);
    unsigned int r = (u + 0x7FFF + ((u >> 16) & 1)) >> 16;   // RNE
    return (unsigned short)r;
}
__device__ __forceinline__ float bf2f(unsigned short u) {
    return __uint_as_float((unsigned int)u << 16);
}

#if __has_builtin(__builtin_amdgcn_exp2f)
#define EXP2(x) __builtin_amdgcn_exp2f(x)
#else
#define EXP2(x) __expf((x) * 0.69314718056f)
#endif

template <int CTRL>
__device__ __forceinline__ float dpp_shr_add(float v) {
    int sh = __builtin_amdgcn_update_dpp(0, __float_as_int(v), CTRL, 0xF, 0xF, true);
    return v + __int_as_float(sh);
}
__device__ __forceinline__ float red16(float c) {
    c = dpp_shr_add<0x111>(c);
    c = dpp_shr_add<0x112>(c);
    c = dpp_shr_add<0x114>(c);
    c = dpp_shr_add<0x118>(c);
    return c;   // lane s==15 of each 16-group holds the sum
}

// ---------------------------------------------------------------------------
// conversions + zero hm + zero counter. 1826 blocks.
// ---------------------------------------------------------------------------
__global__ __launch_bounds__(256) void k_cvt(
    const float* __restrict__ x,  unsigned short* __restrict__ xbf,
    const float* __restrict__ pw, unsigned short* __restrict__ wpin,
    const float* __restrict__ iw, unsigned short* __restrict__ win,
    const float* __restrict__ ow, unsigned short* __restrict__ wout,
    float* __restrict__ hm, unsigned int* __restrict__ cnt)
{
    int bid = blockIdx.x, tid = threadIdx.x;
    if (bid >= 1824) {
        int i = (bid - 1824) * 2048 + tid * 8;
        float4 z = make_float4(0.f, 0.f, 0.f, 0.f);
        *(float4*)(hm + i) = z;
        *(float4*)(hm + i + 4) = z;
        if (bid == 1825 && tid == 0) cnt[0] = 0u;
        return;
    }
    const float* src; unsigned short* dst; int off;
    if      (bid < 256)  { src = x;  dst = xbf;  off = bid; }
    else if (bid < 288)  { src = pw; dst = wpin; off = bid - 256; }
    else if (bid < 1312) { src = iw; dst = win;  off = bid - 288; }
    else                 { src = ow; dst = wout; off = bid - 1312; }
    int i = (off * 256 + tid) * 8;
    float4 a = *(const float4*)(src + i);
    float4 b = *(const float4*)(src + i + 4);
    unsigned short o[8];
    o[0] = f2bf(a.x); o[1] = f2bf(a.y); o[2] = f2bf(a.z); o[3] = f2bf(a.w);
    o[4] = f2bf(b.x); o[5] = f2bf(b.y); o[6] = f2bf(b.z); o[7] = f2bf(b.w);
    *(uint4*)(dst + i) = *(uint4*)o;
}

// ---------------------------------------------------------------------------
// bf16 MFMA GEMM 128x64 (N=512): proj_in and out_proj(l=0). bf16 out.
// ---------------------------------------------------------------------------
__global__ __launch_bounds__(256) void k_gemm_n64(
    const unsigned short* __restrict__ A,
    const unsigned short* __restrict__ W,
    const float* __restrict__ bias,
    unsigned short* __restrict__ Cb, int K)
{
    __shared__ unsigned short As[128 * 40];
    __shared__ unsigned short Ws[64 * 40];

    const int tid   = threadIdx.x;
    const int bxx   = blockIdx.x, byy = blockIdx.y;
    const int arow  = tid >> 1;
    const int ahalf = tid & 1;
    const long aBase = (long)(byy * 128 + arow) * K + ahalf * 16;
    const int  albase = arow * 40 + ahalf * 16;
    const int wrow = tid >> 2;
    const int wq   = tid & 3;
    const long wBase = (long)(bxx * 64 + wrow) * K + wq * 8;
    const int  wlbase = wrow * 40 + wq * 8;

    const int lane = tid & 63;
    const int wv   = tid >> 6;
    const int wm   = wv * 32;
    const int lr   = lane & 15;
    const int q    = lane >> 4;

    floatx4 acc[2][4];
#pragma unroll
    for (int i = 0; i < 2; ++i)
#pragma unroll
        for (int j = 0; j < 4; ++j)
#pragma unroll
            for (int r = 0; r < 4; ++r) acc[i][j][r] = 0.f;

    for (int k0 = 0; k0 < K; k0 += 32) {
        __syncthreads();
        const unsigned short* ap = A + aBase + k0;
        uint4 a0 = *(const uint4*)ap;
        uint4 a1 = *(const uint4*)(ap + 8);
        uint4 w0 = *(const uint4*)(W + wBase + k0);
        *(uint4*)(As + albase)     = a0;
        *(uint4*)(As + albase + 8) = a1;
        *(uint4*)(Ws + wlbase)     = w0;
        __syncthreads();

        bf16x8 af[2], bfr[4];
#pragma unroll
        for (int i = 0; i < 2; ++i)
            af[i] = *(const bf16x8*)(As + (wm + i * 16 + lr) * 40 + q * 8);
#pragma unroll
        for (int j = 0; j < 4; ++j)
            bfr[j] = *(const bf16x8*)(Ws + (j * 16 + lr) * 40 + q * 8);
#pragma unroll
        for (int i = 0; i < 2; ++i)
#pragma unroll
            for (int j = 0; j < 4; ++j)
                acc[i][j] = __builtin_amdgcn_mfma_f32_16x16x32_bf16(
                    af[i], bfr[j], acc[i][j], 0, 0, 0);
    }

    float bj[4] = {0.f, 0.f, 0.f, 0.f};
    if (bias) {
#pragma unroll
        for (int j = 0; j < 4; ++j)
            bj[j] = bias[bxx * 64 + j * 16 + lr];
    }
#pragma unroll
    for (int i = 0; i < 2; ++i) {
#pragma unroll
        for (int r = 0; r < 4; ++r) {
            const int  crow = byy * 128 + wm + i * 16 + q * 4 + r;
            const long base = (long)crow * DM + bxx * 64 + lr;
#pragma unroll
            for (int j = 0; j < 4; ++j)
                Cb[base + j * 16] = f2bf(acc[i][j][r] + bj[j]);
        }
    }
}

// ---------------------------------------------------------------------------
// Final out_proj: meanmode (col-sums/L -> hm atomics) + last-block-done
// classifier (coherent hm readback via atomicAdd(p,0)). Grid dim3(8,32).
// ---------------------------------------------------------------------------
__global__ __launch_bounds__(256) void k_outproj_cls(
    const unsigned short* __restrict__ A,
    const unsigned short* __restrict__ W,
    float* __restrict__ hm, unsigned int* __restrict__ cnt,
    const float* __restrict__ w1, const float* __restrict__ b1,
    const float* __restrict__ w2, const float* __restrict__ b2,
    float* __restrict__ out)
{
    __shared__ unsigned short As[128 * 40];
    __shared__ unsigned short Ws[64 * 40];
    __shared__ float colsum[64];
    __shared__ int last;

    const int tid = threadIdx.x;
    const int bxx = blockIdx.x, byy = blockIdx.y;
    const int K = DI;
    const int arow  = tid >> 1;
    const int ahalf = tid & 1;
    const long aBase = (long)(byy * 128 + arow) * K + ahalf * 16;
    const int  albase = arow * 40 + ahalf * 16;
    const int wrow = tid >> 2;
    const int wq   = tid & 3;
    const long wBase = (long)(bxx * 64 + wrow) * K + wq * 8;
    const int  wlbase = wrow * 40 + wq * 8;

    const int lane = tid & 63;
    const int wv   = tid >> 6;
    const int wm   = wv * 32;
    const int lr   = lane & 15;
    const int q    = lane >> 4;

    floatx4 acc[2][4];
#pragma unroll
    for (int i = 0; i < 2; ++i)
#pragma unroll
        for (int j = 0; j < 4; ++j)
#pragma unroll
            for (int r = 0; r < 4; ++r) acc[i][j][r] = 0.f;

    for (int k0 = 0; k0 < K; k0 += 32) {
        __syncthreads();
        const unsigned short* ap = A + aBase + k0;
        uint4 a0 = *(const uint4*)ap;
        uint4 a1 = *(const uint4*)(ap + 8);
        uint4 w0 = *(const uint4*)(W + wBase + k0);
        *(uint4*)(As + albase)     = a0;
        *(uint4*)(As + albase + 8) = a1;
        *(uint4*)(Ws + wlbase)     = w0;
        __syncthreads();

        bf16x8 af[2], bfr[4];
#pragma unroll
        for (int i = 0; i < 2; ++i)
            af[i] = *(const bf16x8*)(As + (wm + i * 16 + lr) * 40 + q * 8);
#pragma unroll
        for (int j = 0; j < 4; ++j)
            bfr[j] = *(const bf16x8*)(Ws + (j * 16 + lr) * 40 + q * 8);
#pragma unroll
        for (int i = 0; i < 2; ++i)
#pragma unroll
            for (int j = 0; j < 4; ++j)
                acc[i][j] = __builtin_amdgcn_mfma_f32_16x16x32_bf16(
                    af[i], bfr[j], acc[i][j], 0, 0, 0);
    }

    // column sums of this 128x64 tile -> hm[b][col]
    __syncthreads();
    if (tid < 64) colsum[tid] = 0.f;
    __syncthreads();
#pragma unroll
    for (int j = 0; j < 4; ++j) {
        float pp = 0.f;
#pragma unroll
        for (int i = 0; i < 2; ++i)
#pragma unroll
            for (int r = 0; r < 4; ++r) pp += acc[i][j][r];
        atomicAdd(&colsum[j * 16 + lr], pp);
    }
    __syncthreads();
    if (tid < 64) {
        const int b = byy >> 2;
        atomicAdd(&hm[b * DM + bxx * 64 + tid],
                  colsum[tid] * (1.f / (float)L_));
    }
    __syncthreads();

    // last-block-done: the 256th block to finish runs the classifier
    if (tid == 0) {
        __threadfence();
        unsigned int old = atomicAdd(cnt, 1u);
        last = (old == 255u) ? 1 : 0;
    }
    __syncthreads();
    if (!last) return;

    float* shm = (float*)As;        // reuse arena (2 KB needed)
    float* su  = (float*)Ws;
    for (int b = 0; b < B_; ++b) {
        // coherent read of hm (other XCDs' atomics)
        shm[tid]       = atomicAdd(&hm[b * DM + tid], 0.f);
        shm[tid + 256] = atomicAdd(&hm[b * DM + tid + 256], 0.f);
        __syncthreads();
        const int jj = tid >> 2, sl = tid & 3;   // 64 units x 4 slices of 128
        const float* wr = w1 + jj * DM + sl * 128;
        const float* hb = shm + sl * 128;
        float pp = 0.f;
        for (int k = 0; k < 128; k += 4)
            pp += hb[k] * wr[k] + hb[k+1] * wr[k+1]
                + hb[k+2] * wr[k+2] + hb[k+3] * wr[k+3];
        pp += __shfl_xor(pp, 1);
        pp += __shfl_xor(pp, 2);
        if (sl == 0) su[jj] = fmaxf(pp + b1[jj], 0.f) * w2[jj];
        __syncthreads();
        if (tid < 64) {
            float v = su[tid];
#pragma unroll
            for (int off = 32; off; off >>= 1) v += __shfl_down(v, off);
            if (tid == 0) out[b] = v + b2[0];
        }
        __syncthreads();
    }
}

// ---------------------------------------------------------------------------
// bf16 MFMA GEMM 128x128 (in_proj, N=2048, bf16 out). Grid dim3(16,32).
// ---------------------------------------------------------------------------
__global__ __launch_bounds__(256) void k_gemm_128(
    const unsigned short* __restrict__ A,
    const unsigned short* __restrict__ W,
    unsigned short* __restrict__ Cb, int N, int K)
{
    __shared__ unsigned short As[128 * 40];
    __shared__ unsigned short Ws[128 * 40];

    const int tid  = threadIdx.x;
    const int bxx  = blockIdx.x, byy = blockIdx.y;
    const int row  = tid >> 1;
    const int half = tid & 1;
    const long aBase = (long)(byy * 128 + row) * K + half * 16;
    const long wBase = (long)(bxx * 128 + row) * K + half * 16;
    const int  lbase = row * 40 + half * 16;

    const int lane = tid & 63;
    const int wv   = tid >> 6;
    const int wm   = (wv >> 1) * 64;
    const int wn   = (wv & 1) * 64;
    const int lr   = lane & 15;
    const int q    = lane >> 4;

    floatx4 acc[4][4];
#pragma unroll
    for (int i = 0; i < 4; ++i)
#pragma unroll
        for (int j = 0; j < 4; ++j)
#pragma unroll
            for (int r = 0; r < 4; ++r) acc[i][j][r] = 0.f;

    for (int k0 = 0; k0 < K; k0 += 32) {
        __syncthreads();
        const unsigned short* ap = A + aBase + k0;
        const unsigned short* wp = W + wBase + k0;
        uint4 a0 = *(const uint4*)ap;
        uint4 a1 = *(const uint4*)(ap + 8);
        uint4 w0 = *(const uint4*)wp;
        uint4 w1 = *(const uint4*)(wp + 8);
        *(uint4*)(As + lbase)     = a0;
        *(uint4*)(As + lbase + 8) = a1;
        *(uint4*)(Ws + lbase)     = w0;
        *(uint4*)(Ws + lbase + 8) = w1;
        __syncthreads();

        bf16x8 af[4], bfr[4];
#pragma unroll
        for (int i = 0; i < 4; ++i)
            af[i] = *(const bf16x8*)(As + (wm + i * 16 + lr) * 40 + q * 8);
#pragma unroll
        for (int j = 0; j < 4; ++j)
            bfr[j] = *(const bf16x8*)(Ws + (wn + j * 16 + lr) * 40 + q * 8);
#pragma unroll
        for (int i = 0; i < 4; ++i)
#pragma unroll
            for (int j = 0; j < 4; ++j)
                acc[i][j] = __builtin_amdgcn_mfma_f32_16x16x32_bf16(
                    af[i], bfr[j], acc[i][j], 0, 0, 0);
    }

#pragma unroll
    for (int i = 0; i < 4; ++i) {
#pragma unroll
        for (int r = 0; r < 4; ++r) {
            const int  crow = byy * 128 + wm + i * 16 + q * 4 + r;
            const long base = (long)crow * N + bxx * 128 + wn + lr;
#pragma unroll
            for (int j = 0; j < 4; ++j)
                Cb[base + j * 16] = f2bf(acc[i][j][r]);
        }
    }
}

// ---------------------------------------------------------------------------
// Fused conv+silu + x_proj split-K partials. Grid dim3(KS, BL/64).
// ---------------------------------------------------------------------------
__global__ __launch_bounds__(256) void k_xprojconv(
    const unsigned short* __restrict__ xzb, const float* __restrict__ cw,
    const float* __restrict__ cb, const float* __restrict__ W,
    float* __restrict__ P, float* __restrict__ xcout)
{
    __shared__ float As[16][68];
    __shared__ float Ws[16][68];

    const int tid  = threadIdx.x;
    const int tx   = tid & 15;
    const int ty   = tid >> 4;
    const int lrow = tid >> 2;
    const int lk   = (tid & 3) << 2;
    const int kbase = blockIdx.x * (DI / KS);

    const int m = blockIdx.y * 64 + lrow;
    const int t = m & (L_ - 1);
    const float* Wp = W + lrow * DI + kbase + lk;

    float acc[4][4] = {};

    for (int k0 = 0; k0 < DI / KS; k0 += 16) {
        const int dcol = kbase + k0 + lk;
        float4 cbv = *(const float4*)(cb + dcol);
        float sums[4] = {cbv.x, cbv.y, cbv.z, cbv.w};
        float4 cwq[4];
#pragma unroll
        for (int qq = 0; qq < 4; ++qq) cwq[qq] = *(const float4*)(cw + (dcol + qq) * 4);
#pragma unroll
        for (int w = 0; w < 4; ++w) {
            int tw = t - 3 + w;
            if (tw >= 0) {
                const uint2 up = *(const uint2*)(xzb + (long)(m - 3 + w) * (2 * DI) + dcol);
                float x0 = __uint_as_float(up.x << 16);
                float x1 = __uint_as_float(up.x & 0xffff0000u);
                float x2 = __uint_as_float(up.y << 16);
                float x3 = __uint_as_float(up.y & 0xffff0000u);
                sums[0] += ((const float*)&cwq[0])[w] * x0;
                sums[1] += ((const float*)&cwq[1])[w] * x1;
                sums[2] += ((const float*)&cwq[2])[w] * x2;
                sums[3] += ((const float*)&cwq[3])[w] * x3;
            }
        }
        float4 a4;
#pragma unroll
        for (int qq = 0; qq < 4; ++qq)
            ((float*)&a4)[qq] = sums[qq] / (1.f + __expf(-sums[qq]));
        float4 wv = *(const float4*)(Wp + k0);
        *(float4*)(xcout + (long)m * DI + dcol) = a4;

        __syncthreads();
        As[lk + 0][lrow] = a4.x; As[lk + 1][lrow] = a4.y;
        As[lk + 2][lrow] = a4.z; As[lk + 3][lrow] = a4.w;
        Ws[lk + 0][lrow] = wv.x; Ws[lk + 1][lrow] = wv.y;
        Ws[lk + 2][lrow] = wv.z; Ws[lk + 3][lrow] = wv.w;
        __syncthreads();
#pragma unroll
        for (int k = 0; k < 16; ++k) {
            const float4 a44 = *(const float4*)&As[k][ty << 2];
            const float4 w4  = *(const float4*)&Ws[k][tx << 2];
            acc[0][0] += a44.x * w4.x; acc[0][1] += a44.x * w4.y;
            acc[0][2] += a44.x * w4.z; acc[0][3] += a44.x * w4.w;
            acc[1][0] += a44.y * w4.x; acc[1][1] += a44.y * w4.y;
            acc[1][2] += a44.y * w4.z; acc[1][3] += a44.y * w4.w;
            acc[2][0] += a44.z * w4.x; acc[2][1] += a44.z * w4.y;
            acc[2][2] += a44.z * w4.z; acc[2][3] += a44.z * w4.w;
            acc[3][0] += a44.w * w4.x; acc[3][1] += a44.w * w4.y;
            acc[3][2] += a44.w * w4.z; acc[3][3] += a44.w * w4.w;
        }
    }

    float* outp = P + (long)blockIdx.x * (BL * 64)
                + (blockIdx.y * 64 + (ty << 2)) * 64 + (tx << 2);
#pragma unroll
    for (int i = 0; i < 4; ++i)
        *(float4*)(outp + i * 64) = make_float4(acc[i][0], acc[i][1],
                                                acc[i][2], acc[i][3]);
}

__global__ __launch_bounds__(256) void k_reduce(
    const float* __restrict__ P, float* __restrict__ xdbl)
{
    int i = (blockIdx.x * 256 + threadIdx.x) * 4;
    float4 s = *(const float4*)(P + i);
#pragma unroll
    for (int k = 1; k < KS; ++k) {
        float4 pp = *(const float4*)(P + (long)k * (BL * 64) + i);
        s.x += pp.x; s.y += pp.y; s.z += pp.z; s.w += pp.w;
    }
    *(float4*)(xdbl + i) = s;
}

// ---------------------------------------------------------------------------
// Scan v3: CL=128, dtw in registers, software-pipelined sdp/sbc4 reads,
// hoisted exp2s ahead of the state-fma chain, fused gate/D/bf16 epilogue.
// Grid 512 x 256.
// ---------------------------------------------------------------------------
__global__ __launch_bounds__(256) void k_scan(
    const float* __restrict__ xc, const float* __restrict__ xdbl,
    const float* __restrict__ A_log, const float* __restrict__ dtw,
    const float* __restrict__ dtpb, const float* __restrict__ Dm,
    const unsigned short* __restrict__ xzb, unsigned short* __restrict__ ysb16)
{
    __shared__ float  sxd [CL][36];        // 18432 B
    __shared__ float4 sdp [CL / 2][17];    // 17408 B
    __shared__ float4 sbc4[CL / 2][17];    // 17408 B
    __shared__ float  sy  [16][CL + 4];    // 8448 B

    const int tid  = threadIdx.x;
    const int s    = tid & 15;
    const int grp  = tid >> 4;
    const int bd0  = blockIdx.x * 16;
    const int b    = bd0 >> 10;
    const int d0   = bd0 & (DI - 1);
    const int mb0  = b * L_;

    const int j  = tid & 15;
    const int tt = tid >> 4;

    const float a    = -__expf(A_log[(d0 + grp) * DS + s]);
    const float bias = dtpb[d0 + j];
    const float dmv  = Dm[d0 + j];
    float4 wreg[8];
#pragma unroll
    for (int k = 0; k < 8; ++k)
        wreg[k] = *(const float4*)(dtw + (d0 + j) * DTR + k * 4);

    float  rxc[8], rB[8], rC[8], rz[8];
    float2 rxd[8];
#pragma unroll
    for (int i = 0; i < 8; ++i) {
        int m = mb0 + tt + 16 * i;
        rxc[i] = xc[m * DI + d0 + j];
        rxd[i] = *(const float2*)(xdbl + m * 64 + j * 2);
        rB[i]  = xdbl[m * 64 + DTR + j];
        rC[i]  = xdbl[m * 64 + DTR + DS + j];
        rz[i]  = bf2f(xzb[(long)m * (2 * DI) + DI + d0 + j]);
    }

    float state = 0.f;

    for (int c = 0; c < NCH; ++c) {
        const int mbase = mb0 + c * CL;
        float xcur[8], zcur[8];
#pragma unroll
        for (int i = 0; i < 8; ++i) { xcur[i] = rxc[i]; zcur[i] = rz[i]; }

        __syncthreads();   // prev chunk LDS fully consumed
#pragma unroll
        for (int i = 0; i < 8; ++i) {
            int t = tt + 16 * i;
            *(float2*)&sxd[t][j * 2] = rxd[i];
            ((float2*)&sbc4[t >> 1][j])[t & 1] = make_float2(rB[i], rC[i]);
        }
        __syncthreads();

        if (c < NCH - 1) {   // prefetch next chunk (latency hidden by compute)
#pragma unroll
            for (int i = 0; i < 8; ++i) {
                int m = mbase + CL + tt + 16 * i;
                rxc[i] = xc[m * DI + d0 + j];
                rxd[i] = *(const float2*)(xdbl + m * 64 + j * 2);
                rB[i]  = xdbl[m * 64 + DTR + j];
                rC[i]  = xdbl[m * 64 + DTR + DS + j];
                rz[i]  = bf2f(xzb[(long)m * (2 * DI) + DI + d0 + j]);
            }
        }

        // dt-projection once per (t,d): (dt*log2e, dt*xc)
#pragma unroll
        for (int i = 0; i < 8; ++i) {
            int t = tt + 16 * i;
            float acc = bias;
#pragma unroll
            for (int k = 0; k < 8; ++k) {
                float4 xv = *(const float4*)&sxd[t][k * 4];
                acc += xv.x * wreg[k].x + xv.y * wreg[k].y
                     + xv.z * wreg[k].z + xv.w * wreg[k].w;
            }
            float dt = (acc > 20.f) ? acc : __logf(1.f + __expf(acc));
            ((float2*)&sdp[t >> 1][j])[t & 1] =
                make_float2(dt * 1.44269504f, dt * xcur[i]);
        }
        __syncthreads();

        // scan, software-pipelined one t4-iteration ahead
        float4 dp0 = sdp[0][grp], dp1 = sdp[1][grp];
        float4 bc0 = sbc4[0][s],  bc1 = sbc4[1][s];
        for (int t4 = 0; t4 < CL; t4 += 4) {
            const float4 cd0 = dp0, cd1 = dp1, cb0 = bc0, cb1 = bc1;
            if (t4 + 4 < CL) {
                const int t2 = (t4 >> 1) + 2;
                dp0 = sdp[t2][grp];     dp1 = sdp[t2 + 1][grp];
                bc0 = sbc4[t2][s];      bc1 = sbc4[t2 + 1][s];
            }
            // independent work first: exps and u-products
            const float dA0 = EXP2(cd0.x * a), dA1 = EXP2(cd0.z * a);
            const float dA2 = EXP2(cd1.x * a), dA3 = EXP2(cd1.z * a);
            const float u0 = cd0.y * cb0.x, u1 = cd0.w * cb0.z;
            const float u2 = cd1.y * cb1.x, u3 = cd1.w * cb1.z;
            // dependent state chain (4 fmas) + contrib taps
            state = fmaf(dA0, state, u0); float c0 = state * cb0.y;
            state = fmaf(dA1, state, u1); float c1 = state * cb0.w;
            state = fmaf(dA2, state, u2); float c2 = state * cb1.y;
            state = fmaf(dA3, state, u3); float c3 = state * cb1.w;
            float ybuf[4];
            ybuf[0] = red16(c0); ybuf[1] = red16(c1);
            ybuf[2] = red16(c2); ybuf[3] = red16(c3);
            if (s == 15) *(float4*)&sy[grp][t4] = *(float4*)ybuf;
        }
        __syncthreads();

        // fused gate: (y + xc*Dm) * silu(z) -> bf16
#pragma unroll
        for (int i = 0; i < 8; ++i) {
            int t = tt + 16 * i;
            float z = zcur[i];
            float sz = z / (1.f + __expf(-z));
            float val = (sy[j][t] + xcur[i] * dmv) * sz;
            ysb16[(mbase + t) * DI + d0 + j] = f2bf(val);
        }
    }
}

// ---------------------------------------------------------------------------
extern "C" void kernel_launch(void* const* d_in, const int* in_sizes, int n_in,
                              void* d_out, int out_size, void* d_ws, size_t ws_size,
                              hipStream_t stream) {
    const float* x          = (const float*)d_in[0];
    const float* proj_in_w  = (const float*)d_in[1];
    const float* proj_in_b  = (const float*)d_in[2];
    const float* in_proj_w  = (const float*)d_in[3];
    const float* conv_w     = (const float*)d_in[4];
    const float* conv_b     = (const float*)d_in[5];
    const float* x_proj_w   = (const float*)d_in[6];
    const float* dt_proj_w  = (const float*)d_in[7];
    const float* dt_proj_b  = (const float*)d_in[8];
    const float* A_log      = (const float*)d_in[9];
    const float* Dm         = (const float*)d_in[10];
    const float* out_proj_w = (const float*)d_in[11];
    const float* cls_w1     = (const float*)d_in[12];
    const float* cls_b1     = (const float*)d_in[13];
    const float* cls_w2     = (const float*)d_in[14];
    const float* cls_b2     = (const float*)d_in[15];
    float* out = (float*)d_out;

    float* ws   = (float*)d_ws;
    float* h    = ws;                       // layout keeper
    float* xzf  = h    + BL * DM;           // bf16 xz region
    float* xcb  = xzf  + BL * 2 * DI;
    float* xdbl = xcb  + BL * DI;
    float* scr  = xdbl + BL * 64;
    float* hm   = scr  + 2 * BL * DI;
    unsigned int* cnt = (unsigned int*)(hm + B_ * DM);
    float* hmp  = hm + B_ * DM;             // layout keeper (cnt lives here)
    float* xpart = scr;

    unsigned short* xzb = (unsigned short*)xzf;
    unsigned short* u16 = (unsigned short*)(hmp + 64 * DM);
    unsigned short* xbf  = u16;
    unsigned short* hbf  = xbf  + BL * DIN;
    unsigned short* ysbf = hbf  + BL * DM;
    unsigned short* wpin = ysbf + BL * DI;
    unsigned short* win  = wpin + DM * DIN;
    unsigned short* wout = win  + NLAY * 2 * DI * DM;

    k_cvt<<<1826, 256, 0, stream>>>(x, xbf, proj_in_w, wpin, in_proj_w, win,
                                    out_proj_w, wout, hm, cnt);

    k_gemm_n64<<<dim3(8, 32), 256, 0, stream>>>(xbf, wpin, proj_in_b, hbf, DIN);

    for (int l = 0; l < NLAY; ++l) {
        k_gemm_128<<<dim3(16, 32), 256, 0, stream>>>(
            hbf, win + l * 2 * DI * DM, xzb, 2 * DI, DM);
        k_xprojconv<<<dim3(KS, 64), 256, 0, stream>>>(
            xzb, conv_w + l * DI * 4, conv_b + l * DI,
            x_proj_w + l * 64 * DI, xpart, xcb);
        k_reduce<<<256, 256, 0, stream>>>(xpart, xdbl);
        k_scan<<<512, 256, 0, stream>>>(
            xcb, xdbl, A_log + l * DI * DS, dt_proj_w + l * DI * DTR,
            dt_proj_b + l * DI, Dm + l * DI, xzb, ysbf);
        if (l == NLAY - 1) {
            k_outproj_cls<<<dim3(8, 32), 256, 0, stream>>>(
                ysbf, wout + l * DM * DI, hm, cnt,
                cls_w1, cls_b1, cls_w2, cls_b2, out);
        } else {
            k_gemm_n64<<<dim3(8, 32), 256, 0, stream>>>(
                ysbf, wout + l * DM * DI, nullptr, hbf, DI);
        }
    }
}

// Round 15
// 342.565 us; speedup vs baseline: 1.2499x; 1.0941x over previous
//
#include <hip/hip_runtime.h>
#include <hip/hip_bf16.h>

// Dims (fixed by the reference)
#define B_   8
#define L_   512
#define DIN  128
#define DM   512
#define NLAY 2
#define DI   1024     // d_inner
#define DS   16       // d_state
#define DTR  32       // dt_rank
#define BL   (B_ * L_)   // 4096
#define KS   8           // x_proj split-K slices
#define CL   128         // scan chunk length (staged in LDS)
#define NCH  (L_ / CL)   // 4

typedef short bf16x8 __attribute__((ext_vector_type(8)));
typedef float floatx4 __attribute__((ext_vector_type(4)));

__device__ __forceinline__ unsigned short f2bf(float f) {
    unsigned int u = __float_as_uint(f);
    unsigned int r = (u + 0x7FFF + ((u >> 16) & 1)) >> 16;   // RNE
    return (unsigned short)r;
}
__device__ __forceinline__ float bf2f(unsigned short u) {
    return __uint_as_float((unsigned int)u << 16);
}

#if __has_builtin(__builtin_amdgcn_exp2f)
#define EXP2(x) __builtin_amdgcn_exp2f(x)
#else
#define EXP2(x) __expf((x) * 0.69314718056f)
#endif

// ---------------------------------------------------------------------------
// Fused fp32->bf16 conversion (x, proj_in_w, in_proj_w, out_proj_w) + zero hm.
// ---------------------------------------------------------------------------
__global__ __launch_bounds__(256) void cvt_all(
    const float* __restrict__ x,  unsigned short* __restrict__ xbf,
    const float* __restrict__ pw, unsigned short* __restrict__ wpin,
    const float* __restrict__ iw, unsigned short* __restrict__ win,
    const float* __restrict__ ow, unsigned short* __restrict__ wout,
    float* __restrict__ hm)
{
    int bid = blockIdx.x;
    if (bid >= 1824) {
        int i = (bid - 1824) * 2048 + threadIdx.x * 8;
        float4 z = make_float4(0.f, 0.f, 0.f, 0.f);
        *(float4*)(hm + i) = z;
        *(float4*)(hm + i + 4) = z;
        return;
    }
    const float* src; unsigned short* dst; int off;
    if      (bid < 256)  { src = x;  dst = xbf;  off = bid; }
    else if (bid < 288)  { src = pw; dst = wpin; off = bid - 256; }
    else if (bid < 1312) { src = iw; dst = win;  off = bid - 288; }
    else                 { src = ow; dst = wout; off = bid - 1312; }
    int i = (off * 256 + threadIdx.x) * 8;
    float4 a = *(const float4*)(src + i);
    float4 b = *(const float4*)(src + i + 4);
    unsigned short o[8];
    o[0] = f2bf(a.x); o[1] = f2bf(a.y); o[2] = f2bf(a.z); o[3] = f2bf(a.w);
    o[4] = f2bf(b.x); o[5] = f2bf(b.y); o[6] = f2bf(b.z); o[7] = f2bf(b.w);
    *(uint4*)(dst + i) = *(uint4*)o;
}

// ---------------------------------------------------------------------------
// bf16 MFMA GEMM, tile 128x128, BK=32 (in_proj, N=2048).
// ---------------------------------------------------------------------------
__global__ __launch_bounds__(256) void gemm_mfma(
    const unsigned short* __restrict__ A,
    const unsigned short* __restrict__ W,
    float* __restrict__ C, unsigned short* __restrict__ Cb,
    int N, int K)
{
    __shared__ unsigned short As[128 * 40];
    __shared__ unsigned short Ws[128 * 40];

    const int tid  = threadIdx.x;
    const int row  = tid >> 1;
    const int half = tid & 1;
    const long aBase = (long)(blockIdx.y * 128 + row) * K + half * 16;
    const long wBase = (long)(blockIdx.x * 128 + row) * K + half * 16;
    const int  lbase = row * 40 + half * 16;

    const int lane = tid & 63;
    const int wv   = tid >> 6;
    const int wm   = (wv >> 1) * 64;
    const int wn   = (wv & 1) * 64;
    const int lr   = lane & 15;
    const int q    = lane >> 4;

    floatx4 acc[4][4];
#pragma unroll
    for (int i = 0; i < 4; ++i)
#pragma unroll
        for (int j = 0; j < 4; ++j)
#pragma unroll
            for (int r = 0; r < 4; ++r) acc[i][j][r] = 0.f;

    for (int k0 = 0; k0 < K; k0 += 32) {
        __syncthreads();
        const unsigned short* ap = A + aBase + k0;
        const unsigned short* wp = W + wBase + k0;
        uint4 a0 = *(const uint4*)ap;
        uint4 a1 = *(const uint4*)(ap + 8);
        uint4 w0 = *(const uint4*)wp;
        uint4 w1 = *(const uint4*)(wp + 8);
        *(uint4*)(As + lbase)     = a0;
        *(uint4*)(As + lbase + 8) = a1;
        *(uint4*)(Ws + lbase)     = w0;
        *(uint4*)(Ws + lbase + 8) = w1;
        __syncthreads();

        bf16x8 af[4], bfr[4];
#pragma unroll
        for (int i = 0; i < 4; ++i)
            af[i] = *(const bf16x8*)(As + (wm + i * 16 + lr) * 40 + q * 8);
#pragma unroll
        for (int j = 0; j < 4; ++j)
            bfr[j] = *(const bf16x8*)(Ws + (wn + j * 16 + lr) * 40 + q * 8);
#pragma unroll
        for (int i = 0; i < 4; ++i)
#pragma unroll
            for (int j = 0; j < 4; ++j)
                acc[i][j] = __builtin_amdgcn_mfma_f32_16x16x32_bf16(
                    af[i], bfr[j], acc[i][j], 0, 0, 0);
    }

#pragma unroll
    for (int i = 0; i < 4; ++i) {
#pragma unroll
        for (int r = 0; r < 4; ++r) {
            const int  crow = blockIdx.y * 128 + wm + i * 16 + q * 4 + r;
            const long base = (long)crow * N + blockIdx.x * 128 + wn + lr;
#pragma unroll
            for (int j = 0; j < 4; ++j) {
                float v = acc[i][j][r];
                if (C)  C[base + j * 16] = v;
                if (Cb) Cb[base + j * 16] = f2bf(v);
            }
        }
    }
}

// ---------------------------------------------------------------------------
// bf16 MFMA GEMM, tile 128(M)x64(N), BK=32 — N=512 (proj_in, out_proj).
// meanmode: accumulate column sums / L into hm instead of writing C/Cb.
// ---------------------------------------------------------------------------
__global__ __launch_bounds__(256) void gemm_mfma_n64(
    const unsigned short* __restrict__ A,
    const unsigned short* __restrict__ W,
    const float* __restrict__ bias,
    float* __restrict__ C, unsigned short* __restrict__ Cb,
    int N, int K, int meanmode, float* __restrict__ hm)
{
    __shared__ unsigned short As[128 * 40];
    __shared__ unsigned short Ws[64 * 40];
    __shared__ float colsum[64];

    const int tid   = threadIdx.x;
    const int arow  = tid >> 1;
    const int ahalf = tid & 1;
    const long aBase = (long)(blockIdx.y * 128 + arow) * K + ahalf * 16;
    const int  albase = arow * 40 + ahalf * 16;
    const int wrow = tid >> 2;
    const int wq   = tid & 3;
    const long wBase = (long)(blockIdx.x * 64 + wrow) * K + wq * 8;
    const int  wlbase = wrow * 40 + wq * 8;

    const int lane = tid & 63;
    const int wv   = tid >> 6;
    const int wm   = wv * 32;
    const int lr   = lane & 15;
    const int q    = lane >> 4;

    floatx4 acc[2][4];
#pragma unroll
    for (int i = 0; i < 2; ++i)
#pragma unroll
        for (int j = 0; j < 4; ++j)
#pragma unroll
            for (int r = 0; r < 4; ++r) acc[i][j][r] = 0.f;

    for (int k0 = 0; k0 < K; k0 += 32) {
        __syncthreads();
        const unsigned short* ap = A + aBase + k0;
        uint4 a0 = *(const uint4*)ap;
        uint4 a1 = *(const uint4*)(ap + 8);
        uint4 w0 = *(const uint4*)(W + wBase + k0);
        *(uint4*)(As + albase)     = a0;
        *(uint4*)(As + albase + 8) = a1;
        *(uint4*)(Ws + wlbase)     = w0;
        __syncthreads();

        bf16x8 af[2], bfr[4];
#pragma unroll
        for (int i = 0; i < 2; ++i)
            af[i] = *(const bf16x8*)(As + (wm + i * 16 + lr) * 40 + q * 8);
#pragma unroll
        for (int j = 0; j < 4; ++j)
            bfr[j] = *(const bf16x8*)(Ws + (j * 16 + lr) * 40 + q * 8);
#pragma unroll
        for (int i = 0; i < 2; ++i)
#pragma unroll
            for (int j = 0; j < 4; ++j)
                acc[i][j] = __builtin_amdgcn_mfma_f32_16x16x32_bf16(
                    af[i], bfr[j], acc[i][j], 0, 0, 0);
    }

    if (meanmode) {
        if (tid < 64) colsum[tid] = 0.f;
        __syncthreads();
#pragma unroll
        for (int j = 0; j < 4; ++j) {
            float p = 0.f;
#pragma unroll
            for (int i = 0; i < 2; ++i)
#pragma unroll
                for (int r = 0; r < 4; ++r) p += acc[i][j][r];
            atomicAdd(&colsum[j * 16 + lr], p);
        }
        __syncthreads();
        if (tid < 64) {
            const int b = blockIdx.y >> 2;   // 4 row-blocks per batch
            atomicAdd(&hm[b * DM + blockIdx.x * 64 + tid],
                      colsum[tid] * (1.f / (float)L_));
        }
        return;
    }

    float bj[4] = {0.f, 0.f, 0.f, 0.f};
    if (bias) {
#pragma unroll
        for (int j = 0; j < 4; ++j)
            bj[j] = bias[blockIdx.x * 64 + j * 16 + lr];
    }
#pragma unroll
    for (int i = 0; i < 2; ++i) {
#pragma unroll
        for (int r = 0; r < 4; ++r) {
            const int  crow = blockIdx.y * 128 + wm + i * 16 + q * 4 + r;
            const long base = (long)crow * N + blockIdx.x * 64 + lr;
#pragma unroll
            for (int j = 0; j < 4; ++j) {
                float v = acc[i][j][r] + bj[j];
                if (C)  C[base + j * 16] = v;
                if (Cb) Cb[base + j * 16] = f2bf(v);
            }
        }
    }
}

// ---------------------------------------------------------------------------
// Fused causal-conv(k=4)+silu + x_proj split-K stage 1 (partials to P).
// ---------------------------------------------------------------------------
__global__ __launch_bounds__(256) void xprojconv(
    const unsigned short* __restrict__ xzb, const float* __restrict__ cw,
    const float* __restrict__ cb, const float* __restrict__ W,
    float* __restrict__ P, float* __restrict__ xcout)
{
    __shared__ float As[16][68];
    __shared__ float Ws[16][68];

    const int tid  = threadIdx.x;
    const int tx   = tid & 15;
    const int ty   = tid >> 4;
    const int lrow = tid >> 2;
    const int lk   = (tid & 3) << 2;
    const int kbase = blockIdx.x * (DI / KS);

    const int m = blockIdx.y * 64 + lrow;
    const int t = m & (L_ - 1);
    const float* Wp = W + lrow * DI + kbase + lk;

    float acc[4][4] = {};

    for (int k0 = 0; k0 < DI / KS; k0 += 16) {
        const int dcol = kbase + k0 + lk;
        float4 cbv = *(const float4*)(cb + dcol);
        float sums[4] = {cbv.x, cbv.y, cbv.z, cbv.w};
        float4 cwq[4];
#pragma unroll
        for (int q = 0; q < 4; ++q) cwq[q] = *(const float4*)(cw + (dcol + q) * 4);
#pragma unroll
        for (int w = 0; w < 4; ++w) {
            int tw = t - 3 + w;
            if (tw >= 0) {
                const uint2 up = *(const uint2*)(xzb + (long)(m - 3 + w) * (2 * DI) + dcol);
                float x0 = __uint_as_float(up.x << 16);
                float x1 = __uint_as_float(up.x & 0xffff0000u);
                float x2 = __uint_as_float(up.y << 16);
                float x3 = __uint_as_float(up.y & 0xffff0000u);
                sums[0] += ((const float*)&cwq[0])[w] * x0;
                sums[1] += ((const float*)&cwq[1])[w] * x1;
                sums[2] += ((const float*)&cwq[2])[w] * x2;
                sums[3] += ((const float*)&cwq[3])[w] * x3;
            }
        }
        float4 a4;
#pragma unroll
        for (int q = 0; q < 4; ++q)
            ((float*)&a4)[q] = sums[q] / (1.f + __expf(-sums[q]));
        float4 wv = *(const float4*)(Wp + k0);
        *(float4*)(xcout + (long)m * DI + dcol) = a4;

        __syncthreads();
        As[lk + 0][lrow] = a4.x; As[lk + 1][lrow] = a4.y;
        As[lk + 2][lrow] = a4.z; As[lk + 3][lrow] = a4.w;
        Ws[lk + 0][lrow] = wv.x; Ws[lk + 1][lrow] = wv.y;
        Ws[lk + 2][lrow] = wv.z; Ws[lk + 3][lrow] = wv.w;
        __syncthreads();
#pragma unroll
        for (int k = 0; k < 16; ++k) {
            const float4 a44 = *(const float4*)&As[k][ty << 2];
            const float4 w4  = *(const float4*)&Ws[k][tx << 2];
            acc[0][0] += a44.x * w4.x; acc[0][1] += a44.x * w4.y;
            acc[0][2] += a44.x * w4.z; acc[0][3] += a44.x * w4.w;
            acc[1][0] += a44.y * w4.x; acc[1][1] += a44.y * w4.y;
            acc[1][2] += a44.y * w4.z; acc[1][3] += a44.y * w4.w;
            acc[2][0] += a44.z * w4.x; acc[2][1] += a44.z * w4.y;
            acc[2][2] += a44.z * w4.z; acc[2][3] += a44.z * w4.w;
            acc[3][0] += a44.w * w4.x; acc[3][1] += a44.w * w4.y;
            acc[3][2] += a44.w * w4.z; acc[3][3] += a44.w * w4.w;
        }
    }

    float* out = P + (long)blockIdx.x * (BL * 64)
               + (blockIdx.y * 64 + (ty << 2)) * 64 + (tx << 2);
#pragma unroll
    for (int i = 0; i < 4; ++i)
        *(float4*)(out + i * 64) = make_float4(acc[i][0], acc[i][1],
                                               acc[i][2], acc[i][3]);
}

__global__ __launch_bounds__(256) void xproj_reduce(
    const float* __restrict__ P, float* __restrict__ xdbl)
{
    int i = (blockIdx.x * 256 + threadIdx.x) * 4;
    float4 s = *(const float4*)(P + i);
#pragma unroll
    for (int k = 1; k < KS; ++k) {
        float4 p = *(const float4*)(P + (long)k * (BL * 64) + i);
        s.x += p.x; s.y += p.y; s.z += p.z; s.w += p.w;
    }
    *(float4*)(xdbl + i) = s;
}

// ---------------------------------------------------------------------------
template <int CTRL>
__device__ __forceinline__ float dpp_shr_add(float v) {
    int sh = __builtin_amdgcn_update_dpp(0, __float_as_int(v), CTRL, 0xF, 0xF, true);
    return v + __int_as_float(sh);
}

// ---------------------------------------------------------------------------
// Monolithic scan v2 (R9/R11 body, unchanged): paired LDS layout, inline dt,
// register prefetch, fused gate/D/bf16 epilogue. Grid 512 x 256.
// ---------------------------------------------------------------------------
__global__ __launch_bounds__(256) void scan_fused(
    const float* __restrict__ xc, const float* __restrict__ xdbl,
    const float* __restrict__ A_log, const float* __restrict__ dtw,
    const float* __restrict__ dtpb, const float* __restrict__ Dm,
    const unsigned short* __restrict__ xzb, unsigned short* __restrict__ ysb16)
{
    __shared__ float  sdtw[16][36];
    __shared__ float  sxd [CL][36];
    __shared__ float4 sdp [CL / 2][17];
    __shared__ float4 sbc4[CL / 2][17];
    __shared__ float  sy  [16][CL + 4];

    const int tid  = threadIdx.x;
    const int s    = tid & 15;
    const int grp  = tid >> 4;
    const int bd0  = blockIdx.x * 16;
    const int b    = bd0 >> 10;
    const int d0   = bd0 & (DI - 1);
    const int mb0  = b * L_;

    const int j  = tid & 15;
    const int tt = tid >> 4;

    {
        float2 w = *(const float2*)(dtw + (d0 + j) * DTR + tt * 2);
        sdtw[j][tt * 2] = w.x; sdtw[j][tt * 2 + 1] = w.y;
    }
    const float a    = -__expf(A_log[(d0 + grp) * DS + s]);
    const float bias = dtpb[d0 + j];
    const float dmv  = Dm[d0 + j];

    float  rxc[8], rB[8], rC[8], rz[8];
    float2 rxd[8];
#pragma unroll
    for (int i = 0; i < 8; ++i) {
        int m = mb0 + tt + 16 * i;
        rxc[i] = xc[m * DI + d0 + j];
        rxd[i] = *(const float2*)(xdbl + m * 64 + j * 2);
        rB[i]  = xdbl[m * 64 + DTR + j];
        rC[i]  = xdbl[m * 64 + DTR + DS + j];
        rz[i]  = bf2f(xzb[(long)m * (2 * DI) + DI + d0 + j]);
    }

    float state = 0.f;

    for (int c = 0; c < NCH; ++c) {
        const int mbase = mb0 + c * CL;
        float xcur[8], zcur[8];
#pragma unroll
        for (int i = 0; i < 8; ++i) { xcur[i] = rxc[i]; zcur[i] = rz[i]; }

        __syncthreads();
#pragma unroll
        for (int i = 0; i < 8; ++i) {
            int t = tt + 16 * i;
            *(float2*)&sxd[t][j * 2] = rxd[i];
            ((float2*)&sbc4[t >> 1][j])[t & 1] = make_float2(rB[i], rC[i]);
        }
        __syncthreads();

        if (c < NCH - 1) {
#pragma unroll
            for (int i = 0; i < 8; ++i) {
                int m = mbase + CL + tt + 16 * i;
                rxc[i] = xc[m * DI + d0 + j];
                rxd[i] = *(const float2*)(xdbl + m * 64 + j * 2);
                rB[i]  = xdbl[m * 64 + DTR + j];
                rC[i]  = xdbl[m * 64 + DTR + DS + j];
                rz[i]  = bf2f(xzb[(long)m * (2 * DI) + DI + d0 + j]);
            }
        }

        {
            float4 wreg[8];
#pragma unroll
            for (int k = 0; k < 8; ++k) wreg[k] = *(const float4*)&sdtw[j][k * 4];
#pragma unroll
            for (int i = 0; i < 8; ++i) {
                int t = tt + 16 * i;
                float acc = bias;
#pragma unroll
                for (int k = 0; k < 8; ++k) {
                    float4 xv = *(const float4*)&sxd[t][k * 4];
                    acc += xv.x * wreg[k].x + xv.y * wreg[k].y
                         + xv.z * wreg[k].z + xv.w * wreg[k].w;
                }
                float dt = (acc > 20.f) ? acc : __logf(1.f + __expf(acc));
                ((float2*)&sdp[t >> 1][j])[t & 1] =
                    make_float2(dt * 1.44269504f, dt * xcur[i]);
            }
        }
        __syncthreads();

        for (int t4 = 0; t4 < CL; t4 += 4) {
            float ybuf[4];
#pragma unroll
            for (int h = 0; h < 2; ++h) {
                const int t2 = (t4 >> 1) + h;
                const float4 dp = sdp[t2][grp];
                const float4 bc = sbc4[t2][s];
                {
                    const float dA = EXP2(dp.x * a);
                    state = fmaf(dA, state, dp.y * bc.x);
                    float contrib = state * bc.y;
                    contrib = dpp_shr_add<0x111>(contrib);
                    contrib = dpp_shr_add<0x112>(contrib);
                    contrib = dpp_shr_add<0x114>(contrib);
                    contrib = dpp_shr_add<0x118>(contrib);
                    ybuf[h * 2] = contrib;
                }
                {
                    const float dA = EXP2(dp.z * a);
                    state = fmaf(dA, state, dp.w * bc.z);
                    float contrib = state * bc.w;
                    contrib = dpp_shr_add<0x111>(contrib);
                    contrib = dpp_shr_add<0x112>(contrib);
                    contrib = dpp_shr_add<0x114>(contrib);
                    contrib = dpp_shr_add<0x118>(contrib);
                    ybuf[h * 2 + 1] = contrib;
                }
            }
            if (s == 15) *(float4*)&sy[grp][t4] = *(float4*)ybuf;
        }
        __syncthreads();

#pragma unroll
        for (int i = 0; i < 8; ++i) {
            int t = tt + 16 * i;
            float z = zcur[i];
            float sz = z / (1.f + __expf(-z));
            float val = (sy[j][t] + xcur[i] * dmv) * sz;
            ysb16[(mbase + t) * DI + d0 + j] = f2bf(val);
        }
    }
}

// ---------------------------------------------------------------------------
// Classifier head reading pre-accumulated mean hm. 8 blocks x 512 thr.
// ---------------------------------------------------------------------------
__global__ __launch_bounds__(512) void meancls_kernel(
    const float* __restrict__ hm, const float* __restrict__ w1,
    const float* __restrict__ b1, const float* __restrict__ w2,
    const float* __restrict__ b2, float* __restrict__ out)
{
    __shared__ float shm[DM];
    __shared__ float su[64];
    const int b = blockIdx.x, tid = threadIdx.x;
    shm[tid] = hm[b * DM + tid];
    __syncthreads();

    const int j = tid >> 3, sl = tid & 7;
    const float* wr = w1 + j * DM + sl * 64;
    const float* hb = shm + sl * 64;
    float p = 0.f;
    for (int k = 0; k < 64; k += 4)
        p += hb[k] * wr[k] + hb[k+1] * wr[k+1]
           + hb[k+2] * wr[k+2] + hb[k+3] * wr[k+3];
    p += __shfl_xor(p, 1);
    p += __shfl_xor(p, 2);
    p += __shfl_xor(p, 4);
    if (sl == 0) su[j] = fmaxf(p + b1[j], 0.f) * w2[j];
    __syncthreads();
    if (tid < 64) {
        float v = su[tid];
#pragma unroll
        for (int off = 32; off; off >>= 1) v += __shfl_down(v, off);
        if (tid == 0) out[b] = v + b2[0];
    }
}

// ---------------------------------------------------------------------------
extern "C" void kernel_launch(void* const* d_in, const int* in_sizes, int n_in,
                              void* d_out, int out_size, void* d_ws, size_t ws_size,
                              hipStream_t stream) {
    const float* x          = (const float*)d_in[0];
    const float* proj_in_w  = (const float*)d_in[1];
    const float* proj_in_b  = (const float*)d_in[2];
    const float* in_proj_w  = (const float*)d_in[3];
    const float* conv_w     = (const float*)d_in[4];
    const float* conv_b     = (const float*)d_in[5];
    const float* x_proj_w   = (const float*)d_in[6];
    const float* dt_proj_w  = (const float*)d_in[7];
    const float* dt_proj_b  = (const float*)d_in[8];
    const float* A_log      = (const float*)d_in[9];
    const float* Dm         = (const float*)d_in[10];
    const float* out_proj_w = (const float*)d_in[11];
    const float* cls_w1     = (const float*)d_in[12];
    const float* cls_b1     = (const float*)d_in[13];
    const float* cls_w2     = (const float*)d_in[14];
    const float* cls_b2     = (const float*)d_in[15];
    float* out = (float*)d_out;

    float* ws   = (float*)d_ws;
    float* h    = ws;                       // layout keeper
    float* xzf  = h    + BL * DM;           // bf16 xz region
    float* xcb  = xzf  + BL * 2 * DI;
    float* xdbl = xcb  + BL * DI;
    float* scr  = xdbl + BL * 64;
    float* hm   = scr  + 2 * BL * DI;
    float* hmp  = hm   + B_ * DM;           // layout keeper
    unsigned short* xzb  = (unsigned short*)xzf;
    unsigned short* u16  = (unsigned short*)(hmp + 64 * DM);
    unsigned short* xbf  = u16;
    unsigned short* hbf  = xbf  + BL * DIN;
    unsigned short* ysbf = hbf  + BL * DM;
    unsigned short* wpin = ysbf + BL * DI;
    unsigned short* win  = wpin + DM * DIN;
    unsigned short* wout = win  + NLAY * 2 * DI * DM;
    float* xpart = scr;

    cvt_all<<<1826, 256, 0, stream>>>(x, xbf, proj_in_w, wpin,
                                      in_proj_w, win, out_proj_w, wout, hm);

    gemm_mfma_n64<<<dim3(DM / 64, BL / 128), 256, 0, stream>>>(
        xbf, wpin, proj_in_b, nullptr, hbf, DM, DIN, 0, nullptr);

    for (int l = 0; l < NLAY; ++l) {
        gemm_mfma<<<dim3(2 * DI / 128, BL / 128), 256, 0, stream>>>(
            hbf, win + l * 2 * DI * DM, nullptr, xzb, 2 * DI, DM);
        xprojconv<<<dim3(KS, 64), 256, 0, stream>>>(
            xzb, conv_w + l * DI * 4, conv_b + l * DI,
            x_proj_w + l * 64 * DI, xpart, xcb);
        xproj_reduce<<<256, 256, 0, stream>>>(xpart, xdbl);
        scan_fused<<<(B_ * DI) / 16, 256, 0, stream>>>(
            xcb, xdbl, A_log + l * DI * DS, dt_proj_w + l * DI * DTR,
            dt_proj_b + l * DI, Dm + l * DI, xzb, ysbf);
        if (l == NLAY - 1) {
            gemm_mfma_n64<<<dim3(DM / 64, BL / 128), 256, 0, stream>>>(
                ysbf, wout + l * DM * DI, nullptr, nullptr, nullptr,
                DM, DI, 1, hm);
        } else {
            gemm_mfma_n64<<<dim3(DM / 64, BL / 128), 256, 0, stream>>>(
                ysbf, wout + l * DM * DI, nullptr, nullptr, hbf,
                DM, DI, 0, nullptr);
        }
    }

    meancls_kernel<<<B_, 512, 0, stream>>>(hm, cls_w1, cls_b1,
                                           cls_w2, cls_b2, out);
}